// Round 8
// baseline (158.063 us; speedup 1.0000x reference)
//
#include <hip/hip_runtime.h>

// SelfAttention B=2 S=2048 H=16 E=64, fp32 in/out, bf16 MFMA internally.
// Round 8: break the per-tile serialization. R7 kept all LDS in ONE char
// blob, so the waitcnt pass must-aliased the glds prefetch (next buffer)
// with the ds_read frags (current buffer) and inserted vmcnt(0) BEFORE the
// first frag read -> every tile paid full HBM latency serially (~4200
// cyc/tile vs ~600 compute). Fix: (a) K0/K1/V0/V1 as separate __shared__
// arrays + k-loop unrolled x2 (static buffer choice -> no-alias provable);
// (b) body ordered [all cur frag ds_reads -> glds prefetch issue -> compute
// -> barrier] so zero vm-ops are outstanding at frag-read time regardless
// of alias analysis; (c) mask bias table built once in LDS (no per-tile
// mask vm-ops); (d) epilogue transposes via the dead Pq region in 2 passes.
// Kept from R7: 32x32x16 MFMA, q-tile 256 / 8 waves (P wave-private, no
// inner barrier), fixed-shift log2-domain softmax (C=16 in mask bias,
// LOG2E folded into Q), XOR chunk swizzle c^(row&7), stride-72 P rows.

#define BATCH 2
#define SEQ   2048
#define NH    16
#define DE    64
#define LDP   72     // proj internal tile stride + attn P row stride
#define LDOF  68     // O f32 epilogue stride
#define NKT   (SEQ / 64)
#define QT    256    // attn q-tile
#define LOG2E 1.44269504088896340736f

using bf16x8   = __attribute__((ext_vector_type(8))) __bf16;
using bf16x4   = __attribute__((ext_vector_type(4))) __bf16;
using floatx4  = __attribute__((ext_vector_type(4))) float;
using floatx16 = __attribute__((ext_vector_type(16))) float;
using intx4    = __attribute__((ext_vector_type(4))) int;
using ushortx4 = __attribute__((ext_vector_type(4))) unsigned short;
using ushortx8 = __attribute__((ext_vector_type(8))) unsigned short;

__device__ __forceinline__ ushortx4 cvt4(floatx4 f) {
    bf16x4 h = __builtin_convertvector(f, bf16x4);   // RNE packed cvt
    return __builtin_bit_cast(ushortx4, h);
}

// async global->LDS, 16B/lane; lds base wave-uniform (lane i -> base + i*16)
__device__ __forceinline__ void glds16(const unsigned short* g, unsigned short* l) {
    __builtin_amdgcn_global_load_lds(
        (const __attribute__((address_space(1))) unsigned int*)g,
        (__attribute__((address_space(3))) unsigned int*)l, 16, 0, 0);
}

// ---------------------------------------------------------------- projection
// grid = 3072: blockIdx = p*1024 + bh*32 + st. One 64x64 GEMM per block.
// Stores XOR-swizzled: logical 16B chunk c of row r -> physical c^(r&7).
__global__ __launch_bounds__(256) void proj_kernel(
    const float* __restrict__ xq, const float* __restrict__ xk, const float* __restrict__ xv,
    const float* __restrict__ Wq, const float* __restrict__ bq,
    const float* __restrict__ Wk, const float* __restrict__ bk,
    const float* __restrict__ Wv, const float* __restrict__ bv,
    unsigned short* __restrict__ qb, unsigned short* __restrict__ kb,
    unsigned short* __restrict__ vtb)
{
    __shared__ __align__(16) unsigned short Xb[64 * LDP];
    __shared__ __align__(16) unsigned short Wb[64 * LDP];
    __shared__ __align__(16) unsigned short Ob[64 * LDP];
    __shared__ float blds[64];

    const int t  = threadIdx.x;
    const int p  = blockIdx.x >> 10;
    const int bh = (blockIdx.x >> 5) & 31;
    const int st = blockIdx.x & 31;
    const int s0 = st * 64;
    const int b  = bh >> 4, h = bh & 15;
    const int lane = t & 63, w = t >> 6, quad = lane >> 4, l16 = lane & 15;

    const float* x    = (p == 0) ? xq : (p == 1) ? xk : xv;
    const float* W    = (p == 0) ? Wq : (p == 1) ? Wk : Wv;
    const float* bias = (p == 0) ? bq : (p == 1) ? bk : bv;

    #pragma unroll
    for (int i = 0; i < 4; ++i) {
        int idx = i * 1024 + t * 4;
        int row = idx >> 6, col = idx & 63;
        floatx4 xv4 = *(const floatx4*)(x + (((size_t)(b * SEQ + s0 + row) * NH + h) * DE + col));
        *(ushortx4*)&Xb[row * LDP + col] = cvt4(xv4);
        floatx4 wv4 = *(const floatx4*)(W + row * 64 + col);
        *(ushortx4*)&Wb[row * LDP + col] = cvt4(wv4);
    }
    if (t < 64) blds[t] = bias[t];
    __syncthreads();

    if (p < 2) {
        // A = W rows (m=f), B = X rows (n=s) -> D[f][s]
        bf16x8 a0 = *(const bf16x8*)&Wb[(w * 16 + l16) * LDP + quad * 8];
        bf16x8 a1 = *(const bf16x8*)&Wb[(w * 16 + l16) * LDP + 32 + quad * 8];
        floatx4 bf4 = *(const floatx4*)&blds[w * 16 + quad * 4];
        const float scale = (p == 0) ? 0.125f * LOG2E : 1.0f;  // Q in log2 domain
        #pragma unroll
        for (int nb = 0; nb < 4; ++nb) {
            bf16x8 b0 = *(const bf16x8*)&Xb[(nb * 16 + l16) * LDP + quad * 8];
            bf16x8 b1 = *(const bf16x8*)&Xb[(nb * 16 + l16) * LDP + 32 + quad * 8];
            floatx4 c = {0.f, 0.f, 0.f, 0.f};
            c = __builtin_amdgcn_mfma_f32_16x16x32_bf16(a0, b0, c, 0, 0, 0);
            c = __builtin_amdgcn_mfma_f32_16x16x32_bf16(a1, b1, c, 0, 0, 0);
            floatx4 v;
            v[0] = (c[0] + bf4[0]) * scale; v[1] = (c[1] + bf4[1]) * scale;
            v[2] = (c[2] + bf4[2]) * scale; v[3] = (c[3] + bf4[3]) * scale;
            *(ushortx4*)&Ob[(nb * 16 + l16) * LDP + w * 16 + quad * 4] = cvt4(v);  // Ob[s][f]
        }
    } else {
        // A = X rows (m=s), B = W rows (n=f) -> D[s][f]
        bf16x8 a0 = *(const bf16x8*)&Xb[(w * 16 + l16) * LDP + quad * 8];
        bf16x8 a1 = *(const bf16x8*)&Xb[(w * 16 + l16) * LDP + 32 + quad * 8];
        #pragma unroll
        for (int nb = 0; nb < 4; ++nb) {
            bf16x8 b0 = *(const bf16x8*)&Wb[(nb * 16 + l16) * LDP + quad * 8];
            bf16x8 b1 = *(const bf16x8*)&Wb[(nb * 16 + l16) * LDP + 32 + quad * 8];
            floatx4 c = {0.f, 0.f, 0.f, 0.f};
            c = __builtin_amdgcn_mfma_f32_16x16x32_bf16(a0, b0, c, 0, 0, 0);
            c = __builtin_amdgcn_mfma_f32_16x16x32_bf16(a1, b1, c, 0, 0, 0);
            float bw = blds[nb * 16 + l16];
            floatx4 v;
            v[0] = c[0] + bw; v[1] = c[1] + bw; v[2] = c[2] + bw; v[3] = c[3] + bw;
            *(ushortx4*)&Ob[(nb * 16 + l16) * LDP + w * 16 + quad * 4] = cvt4(v);  // Ob[f][s]
        }
    }
    __syncthreads();

    #pragma unroll
    for (int j = 0; j < 2; ++j) {
        int idx = j * 256 + t;
        int row = idx >> 3, c = idx & 7;
        int cp  = (c ^ (row & 7)) * 8;
        ushortx8 v = *(const ushortx8*)&Ob[row * LDP + c * 8];
        if (p < 2) {
            unsigned short* dst = (p == 0) ? qb : kb;
            *(ushortx8*)(dst + ((size_t)bh * SEQ + s0 + row) * DE + cp) = v;       // row = s
        } else {
            *(ushortx8*)(vtb + ((size_t)bh * DE + row) * SEQ + s0 + cp) = v;       // row = e
        }
    }
}

// ---------------------------------------------------------------- attention
// grid = (SEQ/256, BATCH*NH); block = 512 (8 waves, wave w owns q 32w..32w+31)
__global__ __launch_bounds__(512) void attn_kernel(
    const unsigned short* __restrict__ qb, const unsigned short* __restrict__ kb,
    const unsigned short* __restrict__ vtb, const int* __restrict__ mask,
    float* __restrict__ out)
{
    // SEPARATE arrays: waitcnt pass can prove glds(next buf) !alias ds_read(cur buf)
    __shared__ __align__(64) unsigned short K0[64 * 64], K1[64 * 64];
    __shared__ __align__(64) unsigned short V0[64 * 64], V1[64 * 64];
    __shared__ __align__(64) unsigned short Pq[QT * LDP];   // Q stage (unpadded prefix), then P
    __shared__ __align__(64) float Mall[SEQ];               // mask bias table (C=16 folded)

    const int t  = threadIdx.x;
    const int qt = blockIdx.x, bh = blockIdx.y;
    const int b  = bh >> 4, h = bh & 15;
    const int q0 = qt * QT;
    const int lane = t & 63, w = t >> 6;        // w in 0..7
    const int l31 = lane & 31, hl = lane >> 5;  // half-lane select
    const int sw  = l31 & 7;                    // row&7 swizzle key
    const int qrow = w * 32 + l31;              // this lane's q (local)

    const unsigned short* kbase = kb + (size_t)bh * SEQ * DE;
    const unsigned short* vbase = vtb + (size_t)bh * DE * SEQ;
    const unsigned short* qsrc  = qb + ((size_t)bh * SEQ + q0) * DE;
    const int* mrow = mask + b * SEQ;

    // prologue: stage Q (4 glds/wave) + K/V tile 0; build mask-bias table
    #pragma unroll
    for (int u = 0; u < 4; ++u)
        glds16(qsrc + (u * 8 + w) * 512 + lane * 8, Pq + (u * 8 + w) * 512);
    glds16(kbase + (size_t)(w * 8 + (lane >> 3)) * DE + (lane & 7) * 8,  K0 + w * 512);
    glds16(vbase + (size_t)(w * 8 + (lane >> 3)) * SEQ + (lane & 7) * 8, V0 + w * 512);
    {
        intx4 mv = *(const intx4*)(mrow + t * 4);
        floatx4 bias;
        bias[0] = mv[0] ? -16.0f : -1e30f; bias[1] = mv[1] ? -16.0f : -1e30f;
        bias[2] = mv[2] ? -16.0f : -1e30f; bias[3] = mv[3] ? -16.0f : -1e30f;
        *(floatx4*)&Mall[t * 4] = bias;
    }
    __syncthreads();

    // hoist Q B-frags (unpadded 64-short rows, XOR-swizzled chunks)
    bf16x8 qf[4];
    #pragma unroll
    for (int estep = 0; estep < 4; ++estep)
        qf[estep] = *(const bf16x8*)&Pq[qrow * 64 + (((2 * estep + hl) ^ sw) * 8)];
    __syncthreads();   // all waves hoisted before P overwrites the region

    float l_i = 0.f;
    floatx16 oacc[2];
    #pragma unroll
    for (int eh = 0; eh < 2; ++eh)
        #pragma unroll
        for (int r = 0; r < 16; ++r) oacc[eh][r] = 0.f;

    auto body = [&](int kt, const unsigned short* Kc, const unsigned short* Vc,
                    unsigned short* Kn, unsigned short* Vn) {
        // 1. preload ALL cur-tile frags (no vm-ops outstanding here)
        bf16x8 kf[8], vf[8];
        #pragma unroll
        for (int kh = 0; kh < 2; ++kh)
            #pragma unroll
            for (int estep = 0; estep < 4; ++estep)
                kf[kh * 4 + estep] =
                    *(const bf16x8*)&Kc[(kh * 32 + l31) * 64 + (((2 * estep + hl) ^ sw) * 8)];
        #pragma unroll
        for (int eh = 0; eh < 2; ++eh)
            #pragma unroll
            for (int kstep = 0; kstep < 4; ++kstep)
                vf[eh * 4 + kstep] =
                    *(const bf16x8*)&Vc[(eh * 32 + l31) * 64 + (((2 * kstep + hl) ^ sw) * 8)];

        // 2. issue prefetch for tile kt+1 (overlaps all of step 3)
        if (kt + 1 < NKT) {
            const int k1 = (kt + 1) * 64;
            glds16(kbase + (size_t)(k1 + w * 8 + (lane >> 3)) * DE + (lane & 7) * 8,
                   Kn + w * 512);
            glds16(vbase + (size_t)(w * 8 + (lane >> 3)) * SEQ + k1 + (lane & 7) * 8,
                   Vn + w * 512);
        }

        // 3. compute: QK^T (mask bias C-init) -> exp2 -> P -> PV
        const float* Mc = &Mall[kt * 64];
        float sum = 0.f;
        #pragma unroll
        for (int kh = 0; kh < 2; ++kh) {
            floatx16 c;
            #pragma unroll
            for (int g = 0; g < 4; ++g) {   // reg r: key = 32kh + 8*(r>>2) + 4hl + (r&3)
                floatx4 mg = *(const floatx4*)&Mc[kh * 32 + g * 8 + hl * 4];
                c[g * 4 + 0] = mg[0]; c[g * 4 + 1] = mg[1];
                c[g * 4 + 2] = mg[2]; c[g * 4 + 3] = mg[3];
            }
            #pragma unroll
            for (int estep = 0; estep < 4; ++estep)
                c = __builtin_amdgcn_mfma_f32_32x32x16_bf16(kf[kh * 4 + estep], qf[estep], c, 0, 0, 0);
            #pragma unroll
            for (int r = 0; r < 16; ++r) {
                c[r] = __builtin_amdgcn_exp2f(c[r]);
                sum += c[r];
            }
            #pragma unroll
            for (int m = 0; m < 4; ++m) {   // P wave-private stride-72 rows
                floatx4 g4 = {c[4 * m + 0], c[4 * m + 1], c[4 * m + 2], c[4 * m + 3]};
                *(ushortx4*)&Pq[qrow * LDP + (4 * kh + m) * 8 + hl * 4] = cvt4(g4);
            }
        }
        sum += __shfl_xor(sum, 32);
        l_i += sum;
        __asm__ volatile("s_waitcnt lgkmcnt(0)" ::: "memory");

        bf16x8 pf[4];
        #pragma unroll
        for (int kstep = 0; kstep < 4; ++kstep)
            pf[kstep] = *(const bf16x8*)&Pq[qrow * LDP + (2 * kstep + hl) * 8];
        #pragma unroll
        for (int eh = 0; eh < 2; ++eh)
            #pragma unroll
            for (int kstep = 0; kstep < 4; ++kstep)
                oacc[eh] = __builtin_amdgcn_mfma_f32_32x32x16_bf16(vf[eh * 4 + kstep], pf[kstep],
                                                                   oacc[eh], 0, 0, 0);

        // 4. barrier: drains the prefetch AFTER compute -> only residual latency
        __syncthreads();
    };

    for (int kt = 0; kt < NKT; kt += 2) {
        body(kt,     K0, V0, K1, V1);
        body(kt + 1, K1, V1, K0, V0);
    }

    // epilogue: O^T -> Pq-as-float (128 rows/pass, 2 passes) -> coalesced stores
    float invl = __builtin_amdgcn_rcpf(l_i);
    float* Ol = (float*)Pq;                    // 36864B >= 128*LDOF*4 = 34816B
    #pragma unroll
    for (int half = 0; half < 2; ++half) {
        __syncthreads();
        if ((w >> 2) == half) {
            int qr = qrow - half * 128;        // 0..127
            #pragma unroll
            for (int eh = 0; eh < 2; ++eh)
                #pragma unroll
                for (int m = 0; m < 4; ++m) {
                    floatx4 ov;
                    ov[0] = oacc[eh][4 * m + 0] * invl; ov[1] = oacc[eh][4 * m + 1] * invl;
                    ov[2] = oacc[eh][4 * m + 2] * invl; ov[3] = oacc[eh][4 * m + 3] * invl;
                    *(floatx4*)&Ol[qr * LDOF + eh * 32 + m * 8 + hl * 4] = ov;
                }
        }
        __syncthreads();
        #pragma unroll
        for (int pass = 0; pass < 4; ++pass) {
            int idx = pass * 512 + t;
            int rl  = idx >> 4;                // 16 float4-chunks per 64-float row
            int col = (idx & 15) * 4;
            floatx4 tv = *(const floatx4*)&Ol[rl * LDOF + col];
            *(floatx4*)(out + (((size_t)b * SEQ + q0 + half * 128 + rl) * NH + h) * DE + col) = tv;
        }
    }
}

extern "C" void kernel_launch(void* const* d_in, const int* in_sizes, int n_in,
                              void* d_out, int out_size, void* d_ws, size_t ws_size,
                              hipStream_t stream) {
    const float* query = (const float*)d_in[0];
    const float* key   = (const float*)d_in[1];
    const float* value = (const float*)d_in[2];
    const int*   mask  = (const int*)d_in[3];
    const float* Wq = (const float*)d_in[4];
    const float* bq = (const float*)d_in[5];
    const float* Wk = (const float*)d_in[6];
    const float* bk = (const float*)d_in[7];
    const float* Wv = (const float*)d_in[8];
    const float* bv = (const float*)d_in[9];

    const size_t tensor_elems = (size_t)BATCH * NH * SEQ * DE;
    unsigned short* qb  = (unsigned short*)d_ws;
    unsigned short* kb  = qb + tensor_elems;
    unsigned short* vtb = kb + tensor_elems;

    proj_kernel<<<dim3(3 * BATCH * NH * (SEQ / 64)), 256, 0, stream>>>(
        query, key, value, Wq, bq, Wk, bk, Wv, bv, qb, kb, vtb);
    attn_kernel<<<dim3(SEQ / QT, BATCH * NH), 512, 0, stream>>>(
        qb, kb, vtb, mask, (float*)d_out);
}